// Round 4
// baseline (2022.577 us; speedup 1.0000x reference)
//
#include <hip/hip_runtime.h>
#include <cstdint>

#define N_U 100000
#define N_I 50000
#define DIM 64
#define RANK 5
#define NNZ_ 2000000
#define M_U 2048
#define M_I 4096
#define NSEG 150000   // N_U + N_I combined segment count
#define NBUCK 9375    // ceil(NSEG/16); bucket = seg >> 4

// neg-GEMM tiling
#define CPC 3136
#define NCH_U 32
#define NCH_I 16
#define NPAD_U (CPC * NCH_U)
#define NPAD_I (CPC * NCH_I)

typedef __attribute__((ext_vector_type(8))) short short8;
typedef __attribute__((ext_vector_type(4))) float floatx4;

// ---- workspace layout (float offsets) ----
static constexpr size_t ZU1 = 0;                       // 6.4M
static constexpr size_t ZI1 = 6400000;                 // 3.2M
static constexpr size_t EDGE = 9600000;                // 4M entries x 8B = 8M floats
static constexpr size_t P_OFF = 17600000;              // 320
static constexpr size_t Q_OFF = 17600320;              // 320
static constexpr size_t ACC_OFF = 17600640;            // 1 (pad to 704)
static constexpr size_t CNT_OFF = 17600704;            // 150000 ints
static constexpr size_t BCNT_OFF = 17750704;           // 9375 ints
static constexpr size_t ZERO_END = 17760128;           // memset [P_OFF, ZERO_END)
static constexpr size_t OFF_OFF = 17760128;            // 150016 ints
static constexpr size_t BOFF_OFF = 17910144;           // 9375 ints (pad to 17919552)
static constexpr size_t BSUM_OFF = 17919552;           // 1024 ints
static constexpr size_t EU0 = 17920576;                // 6.4M
static constexpr size_t EI0 = EU0 + 6400000;           // 3.2M
static constexpr size_t PART_U = EI0 + 3200000;        // 2048*32
static constexpr size_t PART_I = PART_U + (size_t)M_U * NCH_U;  // 4096*16
// total = 27,651,648 floats = 110.6 MB (< 115.7 MB proven in R1)
// ---- staging overlays, live ONLY during CSR build (before ew_add) ----
static constexpr size_t STAGE_SV = 0;                  // 4M float2 = 8M floats [0, 8M)
static constexpr size_t STAGE_SEG = EU0;               // 4M ints (EU0 written later)
// ---- bf16 overlay inside ZU1 (zu1/zi1 dead after layer-2 spmm) ----
static constexpr size_t EBU16 = 0;                     // 3,211,264 fl
static constexpr size_t EBI16 = 3211264;               // 1,605,632 fl
static constexpr size_t GBU16 = EBI16 + 1605632;       // 65,536 fl
static constexpr size_t GBI16 = GBU16 + 65536;         // 131,072 fl -> end 5,013,504 < 6.4M

static __device__ __forceinline__ short f2bf(float x) {
    unsigned u = __builtin_bit_cast(unsigned, x);
    unsigned r = (u + 0x7fffu + ((u >> 16) & 1u)) >> 16;
    return (short)r;
}

__global__ void ew_add_kernel(const float4* __restrict__ a, const float4* __restrict__ b,
                              float4* __restrict__ o, int n) {
    int i = blockIdx.x * blockDim.x + threadIdx.x;
    if (i < n) {
        float4 x = a[i], y = b[i];
        o[i] = make_float4(x.x + y.x, x.y + y.y, x.z + y.z, x.w + y.w);
    }
}

// ---------- CSR/CSC build ----------
// per-segment AND per-bucket histograms in one pass
__global__ void hist_kernel(const int* __restrict__ rows, const int* __restrict__ cols,
                            int* __restrict__ cnt, int* __restrict__ bcnt) {
    int e = blockIdx.x * blockDim.x + threadIdx.x;
    if (e >= NNZ_) return;
    int r = rows[e], c = cols[e];
    atomicAdd(&cnt[r], 1);
    atomicAdd(&cnt[N_U + c], 1);
    atomicAdd(&bcnt[r >> 4], 1);
    atomicAdd(&bcnt[(N_U + c) >> 4], 1);
}

__global__ void scan1_kernel(const int* __restrict__ cnt, int* __restrict__ bsum, int n) {
    int i = blockIdx.x * 256 + threadIdx.x;
    int v = (i < n) ? cnt[i] : 0;
#pragma unroll
    for (int off = 32; off; off >>= 1) v += __shfl_down(v, off);
    __shared__ int ls[4];
    int lane = threadIdx.x & 63, w = threadIdx.x >> 6;
    if (lane == 0) ls[w] = v;
    __syncthreads();
    if (threadIdx.x == 0) bsum[blockIdx.x] = ls[0] + ls[1] + ls[2] + ls[3];
}

__global__ void scan2_kernel(int* __restrict__ bsum, int nb) {
    __shared__ int s[1024];
    int t = threadIdx.x;
    s[t] = (t < nb) ? bsum[t] : 0;
    __syncthreads();
    for (int off = 1; off < 1024; off <<= 1) {
        int v = (t >= off) ? s[t - off] : 0;
        __syncthreads();
        s[t] += v;
        __syncthreads();
    }
    if (t < nb) bsum[t] = (t == 0) ? 0 : s[t - 1];
}

__global__ void scan3_kernel(const int* __restrict__ cnt, const int* __restrict__ bsum,
                             int* __restrict__ off, int n) {
    __shared__ int s[256];
    int i = blockIdx.x * 256 + threadIdx.x;
    int t = threadIdx.x;
    int c = (i < n) ? cnt[i] : 0;
    s[t] = c;
    __syncthreads();
    for (int o = 1; o < 256; o <<= 1) {
        int v = (t >= o) ? s[t - o] : 0;
        __syncthreads();
        s[t] += v;
        __syncthreads();
    }
    if (i < n) off[i] = bsum[blockIdx.x] + s[t] - c;
}

// pass 1: ticket-scatter (seg, idx, val) into coarse buckets (dense writes)
__global__ void bucket_scatter_kernel(const int* __restrict__ rows, const int* __restrict__ cols,
                                      const float* __restrict__ vals, int* __restrict__ boff,
                                      float2* __restrict__ sv, int* __restrict__ sseg) {
    int e = blockIdx.x * blockDim.x + threadIdx.x;
    if (e >= NNZ_) return;
    int r = rows[e], c = cols[e];
    float v = vals[e];
    int pU = atomicAdd(&boff[r >> 4], 1);
    sv[pU] = make_float2(__int_as_float(c), v);
    sseg[pU] = r;
    int segI = N_U + c;
    int pI = atomicAdd(&boff[segI >> 4], 1);
    sv[pI] = make_float2(__int_as_float(r), v);
    sseg[pI] = segI;
}

// pass 2: one block per bucket; place entries at exact CSR positions
// (random writes confined to the bucket's ~2.5-5 KB destination window)
__global__ __launch_bounds__(256) void place_kernel(const float2* __restrict__ sv,
                                                    const int* __restrict__ sseg,
                                                    const int* __restrict__ boff,
                                                    const int* __restrict__ bcnt,
                                                    int* __restrict__ off,
                                                    float2* __restrict__ edge) {
    int b = blockIdx.x;
    int end = boff[b];          // post-pass-1 ticket value = end
    int start = end - bcnt[b];
    for (int i = start + threadIdx.x; i < end; i += 256) {
        int seg = sseg[i];
        int pos = atomicAdd(&off[seg], 1);
        edge[pos] = sv[i];
    }
}

// wave-per-row CSR SpMM; off[] holds END offsets (post-place), range = [end-cnt, end)
__global__ __launch_bounds__(256) void spmm_csr_kernel(
    const float2* __restrict__ edge, const int* __restrict__ off, const int* __restrict__ cnt,
    int base, const float* __restrict__ Esrc, float* __restrict__ out, float scale, int accum,
    int nrows) {
    int lane = threadIdx.x & 63;
    int row = (blockIdx.x * blockDim.x + threadIdx.x) >> 6;
    if (row >= nrows) return;
    int end = off[base + row];
    int n = cnt[base + row];
    int e = end - n;
    float acc = 0.f;
    for (; e + 4 <= end; e += 4) {
        float2 p0 = edge[e], p1 = edge[e + 1], p2 = edge[e + 2], p3 = edge[e + 3];
        float g0 = Esrc[(size_t)__float_as_int(p0.x) * 64 + lane];
        float g1 = Esrc[(size_t)__float_as_int(p1.x) * 64 + lane];
        float g2 = Esrc[(size_t)__float_as_int(p2.x) * 64 + lane];
        float g3 = Esrc[(size_t)__float_as_int(p3.x) * 64 + lane];
        acc = __builtin_fmaf(p0.y, g0, acc);
        acc = __builtin_fmaf(p1.y, g1, acc);
        acc = __builtin_fmaf(p2.y, g2, acc);
        acc = __builtin_fmaf(p3.y, g3, acc);
    }
    for (; e < end; e++) {
        float2 p = edge[e];
        acc = __builtin_fmaf(p.y, Esrc[(size_t)__float_as_int(p.x) * 64 + lane], acc);
    }
    size_t o = (size_t)row * 64 + lane;
    if (accum) out[o] += scale * acc;
    else out[o] = acc;
}

__global__ void rank_kernel(const float* __restrict__ X, const float* __restrict__ W,
                            float* __restrict__ P, int n) {
    int lane = threadIdx.x & 63;
    int wave = (blockIdx.x * blockDim.x + threadIdx.x) >> 6;
    int nw = (gridDim.x * blockDim.x) >> 6;
    float acc[RANK] = {0.f, 0.f, 0.f, 0.f, 0.f};
    for (int i = wave; i < n; i += nw) {
        float x = X[i * 64 + lane];
#pragma unroll
        for (int r = 0; r < RANK; r++) acc[r] = __builtin_fmaf(W[r * n + i], x, acc[r]);
    }
#pragma unroll
    for (int r = 0; r < RANK; r++) atomicAdd(&P[r * 64 + lane], acc[r]);
}

// out = (a + b) / 3   (layer-2 spmm then adds its term in accumulate mode)
__global__ void pre_out_kernel(const float4* __restrict__ a, const float4* __restrict__ b,
                               float4* __restrict__ o, int n) {
    int i = blockIdx.x * blockDim.x + threadIdx.x;
    if (i < n) {
        float4 x = a[i], y = b[i];
        const float s = 1.f / 3.f;
        o[i] = make_float4((x.x + y.x) * s, (x.y + y.y) * s, (x.z + y.z) * s, (x.w + y.w) * s);
    }
}

__global__ void conv_bf16_kernel(const float* __restrict__ E, short* __restrict__ B, int n64,
                                 int npad64) {
    int i = blockIdx.x * blockDim.x + threadIdx.x;
    if (i < npad64) B[i] = (i < n64) ? f2bf(E[i]) : (short)0;
}

__global__ void gather_kernel(const int* __restrict__ ids, int m, const float* __restrict__ E0,
                              const float* __restrict__ PQ, const float* __restrict__ mulS,
                              const float* __restrict__ Eout, short* __restrict__ Gb,
                              float* __restrict__ acc, float coef) {
    int lane = threadIdx.x & 63;
    int k = (blockIdx.x * blockDim.x + threadIdx.x) >> 6;
    if (k >= m) return;
    int u = ids[k];
    float g = E0[u * 64 + lane];
#pragma unroll
    for (int r = 0; r < RANK; r++) g = __builtin_fmaf(mulS[u * RANK + r], PQ[r * 64 + lane], g);
    g *= (1.f / 3.f);
    Gb[k * 64 + lane] = f2bf(g);
    float d = g * Eout[u * 64 + lane];
#pragma unroll
    for (int off = 32; off; off >>= 1) d += __shfl_down(d, off);
    if (lane == 0) {
        float t = fminf(fmaxf(d * 5.f, -5.f), 5.f);
        atomicAdd(acc, coef * t);
    }
}

__global__ __launch_bounds__(256) void neg_mfma_kernel(const short* __restrict__ G16,
                                                       const short* __restrict__ E16,
                                                       float* __restrict__ part, int nchunk) {
    int lane = threadIdx.x & 63;
    int wave = threadIdx.x >> 6;
    int quad = lane >> 4;
    int rr = lane & 15;
    int rowbase = blockIdx.x * 64 + wave * 16;
    const short8* ga = (const short8*)(G16 + (size_t)(rowbase + rr) * 64 + quad * 8);
    short8 a0 = ga[0];
    short8 a1 = ga[4];
    int c0 = blockIdx.y * CPC;
    float s0 = 0.f, s1 = 0.f, s2 = 0.f, s3 = 0.f;
    for (int ct = 0; ct < CPC; ct += 16) {
        const short8* eb = (const short8*)(E16 + (size_t)(c0 + ct + rr) * 64 + quad * 8);
        short8 b0 = eb[0];
        short8 b1 = eb[4];
        floatx4 acc = {0.f, 0.f, 0.f, 0.f};
        acc = __builtin_amdgcn_mfma_f32_16x16x32_bf16(a0, b0, acc, 0, 0, 0);
        acc = __builtin_amdgcn_mfma_f32_16x16x32_bf16(a1, b1, acc, 0, 0, 0);
        s0 += __expf(acc[0] * 5.f);
        s1 += __expf(acc[1] * 5.f);
        s2 += __expf(acc[2] * 5.f);
        s3 += __expf(acc[3] * 5.f);
    }
#pragma unroll
    for (int m = 8; m; m >>= 1) {
        s0 += __shfl_xor(s0, m);
        s1 += __shfl_xor(s1, m);
        s2 += __shfl_xor(s2, m);
        s3 += __shfl_xor(s3, m);
    }
    if (rr == 0) {
        int row = rowbase + quad * 4;
        float* p = part + (size_t)row * nchunk + blockIdx.y;
        p[0] = s0;
        p[(size_t)nchunk] = s1;
        p[(size_t)2 * nchunk] = s2;
        p[(size_t)3 * nchunk] = s3;
    }
}

__global__ void combine_kernel(const float* __restrict__ part, int m, int nchunk, float pad,
                               float* __restrict__ acc, float coef) {
    int row = blockIdx.x * blockDim.x + threadIdx.x;
    if (row >= m) return;
    float S = 0.f;
    for (int c = 0; c < nchunk; c++) S += part[row * nchunk + c];
    float lse = __logf(S - pad);
    atomicAdd(acc, coef * lse);
}

__global__ void cat_kernel(const float* __restrict__ img, const float* __restrict__ txt,
                           float* __restrict__ out, int nrows) {
    int lane = threadIdx.x & 63;
    int row = (blockIdx.x * blockDim.x + threadIdx.x) >> 6;
    if (row >= nrows) return;
    float a = img[row * 64 + lane], b = txt[row * 64 + lane];
    float sa = a * a, sb = b * b;
#pragma unroll
    for (int msk = 32; msk; msk >>= 1) { sa += __shfl_xor(sa, msk); sb += __shfl_xor(sb, msk); }
    float ia = 1.f / fmaxf(sqrtf(sa), 1e-12f);
    float ib = 1.f / fmaxf(sqrtf(sb), 1e-12f);
    out[row * 64 + lane] += 0.02f * (a * ia + b * ib);
}

__global__ void loss_write_kernel(const float* __restrict__ acc, float* __restrict__ out) {
    out[0] = acc[0];
}

extern "C" void kernel_launch(void* const* d_in, const int* in_sizes, int n_in,
                              void* d_out, int out_size, void* d_ws, size_t ws_size,
                              hipStream_t stream) {
    const float* user_emb = (const float*)d_in[0];
    const float* item_emb = (const float*)d_in[1];
    const float* user_pre = (const float*)d_in[2];
    const float* item_pre = (const float*)d_in[3];
    const float* img_i = (const float*)d_in[4];
    const float* txt_i = (const float*)d_in[5];
    const float* img_u = (const float*)d_in[6];
    const float* txt_u = (const float*)d_in[7];
    const int* rows = (const int*)d_in[8];
    const int* cols = (const int*)d_in[9];
    const float* vals = (const float*)d_in[10];
    const float* ut = (const float*)d_in[11];
    const float* vt = (const float*)d_in[12];
    const float* u_mul_s = (const float*)d_in[13];
    const float* v_mul_s = (const float*)d_in[14];
    const int* uids = (const int*)d_in[15];
    const int* iids = (const int*)d_in[16];

    float* ws = (float*)d_ws;
    float* zu1 = ws + ZU1;
    float* zi1 = ws + ZI1;
    float2* edge = (float2*)(ws + EDGE);
    float* P = ws + P_OFF;
    float* Q = ws + Q_OFF;
    float* acc = ws + ACC_OFF;
    int* cnt = (int*)(ws + CNT_OFF);
    int* bcnt = (int*)(ws + BCNT_OFF);
    int* off = (int*)(ws + OFF_OFF);
    int* boff = (int*)(ws + BOFF_OFF);
    int* bsum = (int*)(ws + BSUM_OFF);
    float* eu0 = ws + EU0;
    float* ei0 = ws + EI0;
    float* part_u = ws + PART_U;
    float* part_i = ws + PART_I;
    float2* stage_sv = (float2*)(ws + STAGE_SV);
    int* stage_seg = (int*)(ws + STAGE_SEG);
    short* ebu16 = (short*)(ws + EBU16);
    short* ebi16 = (short*)(ws + EBI16);
    short* gbu16 = (short*)(ws + GBU16);
    short* gbi16 = (short*)(ws + GBI16);

    float* out_u = (float*)d_out;
    float* out_i = out_u + (size_t)N_U * 64;
    float* out_loss = out_u + (size_t)(N_U + N_I) * 64;

    const int NB = (NSEG + 255) / 256;    // 586 seg-scan blocks
    const int NB2 = (NBUCK + 255) / 256;  // 37 bucket-scan blocks

    // zero P,Q,acc,cnt,bcnt
    hipMemsetAsync(ws + P_OFF, 0, (ZERO_END - P_OFF) * sizeof(float), stream);

    // ---- CSR/CSC build (before ew_add: staging overlays ZU1 + EU0 regions) ----
    hist_kernel<<<(NNZ_ + 255) / 256, 256, 0, stream>>>(rows, cols, cnt, bcnt);
    scan1_kernel<<<NB, 256, 0, stream>>>(cnt, bsum, NSEG);
    scan2_kernel<<<1, 1024, 0, stream>>>(bsum, NB);
    scan3_kernel<<<NB, 256, 0, stream>>>(cnt, bsum, off, NSEG);
    scan1_kernel<<<NB2, 256, 0, stream>>>(bcnt, bsum, NBUCK);
    scan2_kernel<<<1, 1024, 0, stream>>>(bsum, NB2);
    scan3_kernel<<<NB2, 256, 0, stream>>>(bcnt, bsum, boff, NBUCK);
    bucket_scatter_kernel<<<(NNZ_ + 255) / 256, 256, 0, stream>>>(rows, cols, vals, boff,
                                                                  stage_sv, stage_seg);
    place_kernel<<<NBUCK, 256, 0, stream>>>(stage_sv, stage_seg, boff, bcnt, off, edge);

    // E0 = pre + emb (staging now dead)
    ew_add_kernel<<<6250, 256, 0, stream>>>((const float4*)user_emb, (const float4*)user_pre,
                                            (float4*)eu0, 1600000);
    ew_add_kernel<<<3125, 256, 0, stream>>>((const float4*)item_emb, (const float4*)item_pre,
                                            (float4*)ei0, 800000);
    // layer-1 rank reductions
    rank_kernel<<<256, 256, 0, stream>>>(ei0, vt, P, N_I);
    rank_kernel<<<256, 256, 0, stream>>>(eu0, ut, Q, N_U);
    // layer-1 SpMM (CSR, no atomics)
    spmm_csr_kernel<<<N_U / 4, 256, 0, stream>>>(edge, off, cnt, 0, ei0, zu1, 1.f, 0, N_U);
    spmm_csr_kernel<<<N_I / 4, 256, 0, stream>>>(edge, off, cnt, N_U, eu0, zi1, 1.f, 0, N_I);
    // layer-2 rank reductions
    rank_kernel<<<256, 256, 0, stream>>>(zi1, vt, P, N_I);
    rank_kernel<<<256, 256, 0, stream>>>(zu1, ut, Q, N_U);
    // out = (E0 + Z1)/3, then layer-2 SpMM accumulates Z2/3 into out
    pre_out_kernel<<<6250, 256, 0, stream>>>((const float4*)eu0, (const float4*)zu1,
                                             (float4*)out_u, 1600000);
    pre_out_kernel<<<3125, 256, 0, stream>>>((const float4*)ei0, (const float4*)zi1,
                                             (float4*)out_i, 800000);
    spmm_csr_kernel<<<N_U / 4, 256, 0, stream>>>(edge, off, cnt, 0, zi1, out_u, 1.f / 3.f, 1,
                                                 N_U);
    spmm_csr_kernel<<<N_I / 4, 256, 0, stream>>>(edge, off, cnt, N_U, zu1, out_i, 1.f / 3.f, 1,
                                                 N_I);
    // bf16 copies of E (overlay in dead zu1 region; zero-padded tail rows)
    conv_bf16_kernel<<<(NPAD_U * 64 + 255) / 256, 256, 0, stream>>>(out_u, ebu16, N_U * 64,
                                                                   NPAD_U * 64);
    conv_bf16_kernel<<<(NPAD_I * 64 + 255) / 256, 256, 0, stream>>>(out_i, ebi16, N_I * 64,
                                                                   NPAD_I * 64);
    // sampled G rows (bf16) + pos term (fp32)
    gather_kernel<<<M_U / 4, 256, 0, stream>>>(uids, M_U, eu0, P, u_mul_s, out_u, gbu16, acc,
                                               -4.f / M_U);
    gather_kernel<<<M_I / 4, 256, 0, stream>>>(iids, M_I, ei0, Q, v_mul_s, out_i, gbi16, acc,
                                               -4.f / M_I);
    // neg term: MFMA exp-sum
    dim3 gu(M_U / 64, NCH_U);
    neg_mfma_kernel<<<gu, 256, 0, stream>>>(gbu16, ebu16, part_u, NCH_U);
    dim3 gi(M_I / 64, NCH_I);
    neg_mfma_kernel<<<gi, 256, 0, stream>>>(gbi16, ebi16, part_i, NCH_I);
    combine_kernel<<<(M_U + 255) / 256, 256, 0, stream>>>(part_u, M_U, NCH_U,
                                                          (float)(NPAD_U - N_U), acc, 4.f / M_U);
    combine_kernel<<<(M_I + 255) / 256, 256, 0, stream>>>(part_i, M_I, NCH_I,
                                                          (float)(NPAD_I - N_I), acc, 4.f / M_I);
    // cat-rate terms (after loss consumed E from d_out)
    cat_kernel<<<(N_U * 64 + 255) / 256, 256, 0, stream>>>(img_u, txt_u, out_u, N_U);
    cat_kernel<<<(N_I * 64 + 255) / 256, 256, 0, stream>>>(img_i, txt_i, out_i, N_I);
    loss_write_kernel<<<1, 1, 0, stream>>>(acc, out_loss);
}

// Round 5
// 1598.874 us; speedup vs baseline: 1.2650x; 1.2650x over previous
//
#include <hip/hip_runtime.h>
#include <cstdint>

#define N_U 100000
#define N_I 50000
#define DIM 64
#define RANK 5
#define NNZ_ 2000000
#define M_U 2048
#define M_I 4096
#define NSEG 150000   // N_U + N_I combined segment count
#define NBUCK 9375    // NSEG/16 exactly; bucket = seg >> 4
#define NPB 64        // place blocks
#define CH 31250      // edges per place block (NNZ_/NPB)

// neg-GEMM tiling
#define CPC 3136
#define NCH_U 32
#define NCH_I 16
#define NPAD_U (CPC * NCH_U)
#define NPAD_I (CPC * NCH_I)

typedef __attribute__((ext_vector_type(8))) short short8;
typedef __attribute__((ext_vector_type(4))) float floatx4;

// ---- workspace layout (float offsets) ----
static constexpr size_t ZU1 = 0;                       // 6.4M
static constexpr size_t ZI1 = 6400000;                 // 3.2M
static constexpr size_t EDGE = 9600000;                // 4M float2 = 8M floats
static constexpr size_t P_OFF = 17600000;              // 320
static constexpr size_t Q_OFF = 17600320;              // 320
static constexpr size_t ACC_OFF = 17600640;            // 1 (pad to 704)
static constexpr size_t CNT_OFF = 17600704;            // 150000 ints
static constexpr size_t OFF_OFF = 17750704;            // 150016 ints
static constexpr size_t BCNT_OFF = 17900720;           // 9375 ints
static constexpr size_t BOFF_OFF = 17910144;           // 9375 ints
static constexpr size_t BSUM_OFF = 17919552;           // 1024 ints
static constexpr size_t EU0 = 17920576;                // 6.4M
static constexpr size_t EI0 = EU0 + 6400000;           // 3.2M
static constexpr size_t PART_U = EI0 + 3200000;        // 2048*32
static constexpr size_t PART_I = PART_U + (size_t)M_U * NCH_U;  // 4096*16
static constexpr size_t BH_OFF = PART_I + (size_t)M_I * NCH_I;  // 64*9375 ints
static constexpr size_t BHP_OFF = BH_OFF + (size_t)NPB * NBUCK; // 64*9375 ints
// end = 28,851,648 floats = 115.4 MB (< 115.7 MB proven in R1)
// ---- staging overlay, live ONLY during CSR build (before spmm) ----
static constexpr size_t STAGE_SV = 0;                  // 4M float2 = [0, 8M) over ZU1+ZI1
// ---- bf16 overlay inside ZU1 (zu1/zi1 dead after layer-2 spmm) ----
static constexpr size_t EBU16 = 0;                     // 3,211,264 fl
static constexpr size_t EBI16 = 3211264;               // 1,605,632 fl
static constexpr size_t GBU16 = EBI16 + 1605632;       // 65,536 fl
static constexpr size_t GBI16 = GBU16 + 65536;         // 131,072 fl -> end 5,013,504 < 6.4M

static __device__ __forceinline__ short f2bf(float x) {
    unsigned u = __builtin_bit_cast(unsigned, x);
    unsigned r = (u + 0x7fffu + ((u >> 16) & 1u)) >> 16;
    return (short)r;
}

__global__ void ew_add_kernel(const float4* __restrict__ a, const float4* __restrict__ b,
                              float4* __restrict__ o, int n) {
    int i = blockIdx.x * blockDim.x + threadIdx.x;
    if (i < n) {
        float4 x = a[i], y = b[i];
        o[i] = make_float4(x.x + y.x, x.y + y.y, x.z + y.z, x.w + y.w);
    }
}

// ---------- atomic-free CSR/CSC build ----------
// phase 1: per-block LDS bucket histogram, dense writeout bh[block][bucket]
__global__ __launch_bounds__(256) void bhist_kernel(const int* __restrict__ rows,
                                                    const int* __restrict__ cols,
                                                    int* __restrict__ bh) {
    __shared__ int h[NBUCK];
    for (int i = threadIdx.x; i < NBUCK; i += 256) h[i] = 0;
    __syncthreads();
    int b = blockIdx.x;
    int lo = b * CH, hi = min(lo + CH, NNZ_);
    for (int e = lo + threadIdx.x; e < hi; e += 256) {
        atomicAdd(&h[rows[e] >> 4], 1);
        atomicAdd(&h[(N_U + cols[e]) >> 4], 1);
    }
    __syncthreads();
    for (int i = threadIdx.x; i < NBUCK; i += 256) bh[(size_t)b * NBUCK + i] = h[i];
}

// phase 2: one wave per bucket: exclusive scan of bh over the 64 blocks -> bhp, total -> bcnt
__global__ __launch_bounds__(256) void bucket_offsets_kernel(const int* __restrict__ bh,
                                                             int* __restrict__ bhp,
                                                             int* __restrict__ bcnt) {
    int lane = threadIdx.x & 63;
    int bucket = (blockIdx.x * blockDim.x + threadIdx.x) >> 6;
    if (bucket >= NBUCK) return;
    int v = bh[(size_t)lane * NBUCK + bucket];
    int x = v;
#pragma unroll
    for (int off = 1; off < 64; off <<= 1) {
        int y = __shfl_up(x, off);
        if (lane >= off) x += y;
    }
    bhp[(size_t)lane * NBUCK + bucket] = x - v;  // exclusive prefix
    if (lane == 63) bcnt[bucket] = x;
}

__global__ void scan1_kernel(const int* __restrict__ cnt, int* __restrict__ bsum, int n) {
    int i = blockIdx.x * 256 + threadIdx.x;
    int v = (i < n) ? cnt[i] : 0;
#pragma unroll
    for (int off = 32; off; off >>= 1) v += __shfl_down(v, off);
    __shared__ int ls[4];
    int lane = threadIdx.x & 63, w = threadIdx.x >> 6;
    if (lane == 0) ls[w] = v;
    __syncthreads();
    if (threadIdx.x == 0) bsum[blockIdx.x] = ls[0] + ls[1] + ls[2] + ls[3];
}

__global__ void scan2_kernel(int* __restrict__ bsum, int nb) {
    __shared__ int s[1024];
    int t = threadIdx.x;
    s[t] = (t < nb) ? bsum[t] : 0;
    __syncthreads();
    for (int off = 1; off < 1024; off <<= 1) {
        int v = (t >= off) ? s[t - off] : 0;
        __syncthreads();
        s[t] += v;
        __syncthreads();
    }
    if (t < nb) bsum[t] = (t == 0) ? 0 : s[t - 1];
}

__global__ void scan3_kernel(const int* __restrict__ cnt, const int* __restrict__ bsum,
                             int* __restrict__ off, int n) {
    __shared__ int s[256];
    int i = blockIdx.x * 256 + threadIdx.x;
    int t = threadIdx.x;
    int c = (i < n) ? cnt[i] : 0;
    s[t] = c;
    __syncthreads();
    for (int o = 1; o < 256; o <<= 1) {
        int v = (t >= o) ? s[t - o] : 0;
        __syncthreads();
        s[t] += v;
        __syncthreads();
    }
    if (i < n) off[i] = bsum[blockIdx.x] + s[t] - c;
}

// phase 3: deterministic placement into bucket-grouped staging (no global atomics).
// entry = (idx | (seg&15)<<20, val) -- idx < 2^20, nibble recovers segment in place2.
__global__ __launch_bounds__(256) void bucket_place_kernel(
    const int* __restrict__ rows, const int* __restrict__ cols, const float* __restrict__ vals,
    const int* __restrict__ boff, const int* __restrict__ bhp, float2* __restrict__ sv) {
    __shared__ int h[NBUCK];
    for (int i = threadIdx.x; i < NBUCK; i += 256) h[i] = 0;
    __syncthreads();
    int b = blockIdx.x;
    int lo = b * CH, hi = min(lo + CH, NNZ_);
    const int* bhpb = bhp + (size_t)b * NBUCK;
    for (int e = lo + threadIdx.x; e < hi; e += 256) {
        int r = rows[e], c = cols[e];
        float v = vals[e];
        int bu = r >> 4;
        int ru = atomicAdd(&h[bu], 1);
        sv[boff[bu] + bhpb[bu] + ru] = make_float2(__int_as_float(c | ((r & 15) << 20)), v);
        int sI = N_U + c;
        int bi = sI >> 4;
        int ri = atomicAdd(&h[bi], 1);
        sv[boff[bi] + bhpb[bi] + ri] = make_float2(__int_as_float(r | ((sI & 15) << 20)), v);
    }
}

// phase 4: one block per bucket: exact CSR placement of its <=~1K entries,
// emit per-segment cnt and end-offsets (random writes confined to ~5 KB window)
__global__ __launch_bounds__(256) void place2_kernel(const float2* __restrict__ sv,
                                                     const int* __restrict__ boff,
                                                     const int* __restrict__ bcnt,
                                                     int* __restrict__ off, int* __restrict__ cnt,
                                                     float2* __restrict__ edge) {
    int b = blockIdx.x;
    int start = boff[b], n = bcnt[b];
    __shared__ int h[16], hs[16], hc[16];
    if (threadIdx.x < 16) { h[threadIdx.x] = 0; hc[threadIdx.x] = 0; }
    __syncthreads();
    for (int i = start + threadIdx.x; i < start + n; i += 256) {
        int packed = __float_as_int(sv[i].x);
        atomicAdd(&h[(packed >> 20) & 15], 1);
    }
    __syncthreads();
    if (threadIdx.x == 0) {
        int run = 0;
#pragma unroll
        for (int k = 0; k < 16; k++) { hs[k] = run; run += h[k]; }
    }
    __syncthreads();
    if (threadIdx.x < 16) {
        int seg = b * 16 + threadIdx.x;
        cnt[seg] = h[threadIdx.x];
        off[seg] = start + hs[threadIdx.x] + h[threadIdx.x];  // END offsets (spmm convention)
    }
    for (int i = start + threadIdx.x; i < start + n; i += 256) {
        float2 p = sv[i];
        int packed = __float_as_int(p.x);
        int s = (packed >> 20) & 15;
        int r = atomicAdd(&hc[s], 1);
        edge[start + hs[s] + r] = make_float2(__int_as_float(packed & 0xFFFFF), p.y);
    }
}

// wave-per-row CSR SpMM; off[] holds END offsets, range = [end-cnt, end)
__global__ __launch_bounds__(256) void spmm_csr_kernel(
    const float2* __restrict__ edge, const int* __restrict__ off, const int* __restrict__ cnt,
    int base, const float* __restrict__ Esrc, float* __restrict__ out, float scale, int accum,
    int nrows) {
    int lane = threadIdx.x & 63;
    int row = (blockIdx.x * blockDim.x + threadIdx.x) >> 6;
    if (row >= nrows) return;
    int end = off[base + row];
    int n = cnt[base + row];
    int e = end - n;
    float acc = 0.f;
    for (; e + 4 <= end; e += 4) {
        float2 p0 = edge[e], p1 = edge[e + 1], p2 = edge[e + 2], p3 = edge[e + 3];
        float g0 = Esrc[(size_t)__float_as_int(p0.x) * 64 + lane];
        float g1 = Esrc[(size_t)__float_as_int(p1.x) * 64 + lane];
        float g2 = Esrc[(size_t)__float_as_int(p2.x) * 64 + lane];
        float g3 = Esrc[(size_t)__float_as_int(p3.x) * 64 + lane];
        acc = __builtin_fmaf(p0.y, g0, acc);
        acc = __builtin_fmaf(p1.y, g1, acc);
        acc = __builtin_fmaf(p2.y, g2, acc);
        acc = __builtin_fmaf(p3.y, g3, acc);
    }
    for (; e < end; e++) {
        float2 p = edge[e];
        acc = __builtin_fmaf(p.y, Esrc[(size_t)__float_as_int(p.x) * 64 + lane], acc);
    }
    size_t o = (size_t)row * 64 + lane;
    if (accum) out[o] += scale * acc;
    else out[o] = acc;
}

__global__ void rank_kernel(const float* __restrict__ X, const float* __restrict__ W,
                            float* __restrict__ P, int n) {
    int lane = threadIdx.x & 63;
    int wave = (blockIdx.x * blockDim.x + threadIdx.x) >> 6;
    int nw = (gridDim.x * blockDim.x) >> 6;
    float acc[RANK] = {0.f, 0.f, 0.f, 0.f, 0.f};
    for (int i = wave; i < n; i += nw) {
        float x = X[i * 64 + lane];
#pragma unroll
        for (int r = 0; r < RANK; r++) acc[r] = __builtin_fmaf(W[r * n + i], x, acc[r]);
    }
#pragma unroll
    for (int r = 0; r < RANK; r++) atomicAdd(&P[r * 64 + lane], acc[r]);
}

__global__ void pre_out_kernel(const float4* __restrict__ a, const float4* __restrict__ b,
                               float4* __restrict__ o, int n) {
    int i = blockIdx.x * blockDim.x + threadIdx.x;
    if (i < n) {
        float4 x = a[i], y = b[i];
        const float s = 1.f / 3.f;
        o[i] = make_float4((x.x + y.x) * s, (x.y + y.y) * s, (x.z + y.z) * s, (x.w + y.w) * s);
    }
}

__global__ void conv_bf16_kernel(const float* __restrict__ E, short* __restrict__ B, int n64,
                                 int npad64) {
    int i = blockIdx.x * blockDim.x + threadIdx.x;
    if (i < npad64) B[i] = (i < n64) ? f2bf(E[i]) : (short)0;
}

__global__ void gather_kernel(const int* __restrict__ ids, int m, const float* __restrict__ E0,
                              const float* __restrict__ PQ, const float* __restrict__ mulS,
                              const float* __restrict__ Eout, short* __restrict__ Gb,
                              float* __restrict__ acc, float coef) {
    int lane = threadIdx.x & 63;
    int k = (blockIdx.x * blockDim.x + threadIdx.x) >> 6;
    if (k >= m) return;
    int u = ids[k];
    float g = E0[u * 64 + lane];
#pragma unroll
    for (int r = 0; r < RANK; r++) g = __builtin_fmaf(mulS[u * RANK + r], PQ[r * 64 + lane], g);
    g *= (1.f / 3.f);
    Gb[k * 64 + lane] = f2bf(g);
    float d = g * Eout[u * 64 + lane];
#pragma unroll
    for (int off = 32; off; off >>= 1) d += __shfl_down(d, off);
    if (lane == 0) {
        float t = fminf(fmaxf(d * 5.f, -5.f), 5.f);
        atomicAdd(acc, coef * t);
    }
}

__global__ __launch_bounds__(256) void neg_mfma_kernel(const short* __restrict__ G16,
                                                       const short* __restrict__ E16,
                                                       float* __restrict__ part, int nchunk) {
    int lane = threadIdx.x & 63;
    int wave = threadIdx.x >> 6;
    int quad = lane >> 4;
    int rr = lane & 15;
    int rowbase = blockIdx.x * 64 + wave * 16;
    const short8* ga = (const short8*)(G16 + (size_t)(rowbase + rr) * 64 + quad * 8);
    short8 a0 = ga[0];
    short8 a1 = ga[4];
    int c0 = blockIdx.y * CPC;
    float s0 = 0.f, s1 = 0.f, s2 = 0.f, s3 = 0.f;
    for (int ct = 0; ct < CPC; ct += 16) {
        const short8* eb = (const short8*)(E16 + (size_t)(c0 + ct + rr) * 64 + quad * 8);
        short8 b0 = eb[0];
        short8 b1 = eb[4];
        floatx4 acc = {0.f, 0.f, 0.f, 0.f};
        acc = __builtin_amdgcn_mfma_f32_16x16x32_bf16(a0, b0, acc, 0, 0, 0);
        acc = __builtin_amdgcn_mfma_f32_16x16x32_bf16(a1, b1, acc, 0, 0, 0);
        s0 += __expf(acc[0] * 5.f);
        s1 += __expf(acc[1] * 5.f);
        s2 += __expf(acc[2] * 5.f);
        s3 += __expf(acc[3] * 5.f);
    }
#pragma unroll
    for (int m = 8; m; m >>= 1) {
        s0 += __shfl_xor(s0, m);
        s1 += __shfl_xor(s1, m);
        s2 += __shfl_xor(s2, m);
        s3 += __shfl_xor(s3, m);
    }
    if (rr == 0) {
        int row = rowbase + quad * 4;
        float* p = part + (size_t)row * nchunk + blockIdx.y;
        p[0] = s0;
        p[(size_t)nchunk] = s1;
        p[(size_t)2 * nchunk] = s2;
        p[(size_t)3 * nchunk] = s3;
    }
}

__global__ void combine_kernel(const float* __restrict__ part, int m, int nchunk, float pad,
                               float* __restrict__ acc, float coef) {
    int row = blockIdx.x * blockDim.x + threadIdx.x;
    if (row >= m) return;
    float S = 0.f;
    for (int c = 0; c < nchunk; c++) S += part[row * nchunk + c];
    float lse = __logf(S - pad);
    atomicAdd(acc, coef * lse);
}

__global__ void cat_kernel(const float* __restrict__ img, const float* __restrict__ txt,
                           float* __restrict__ out, int nrows) {
    int lane = threadIdx.x & 63;
    int row = (blockIdx.x * blockDim.x + threadIdx.x) >> 6;
    if (row >= nrows) return;
    float a = img[row * 64 + lane], b = txt[row * 64 + lane];
    float sa = a * a, sb = b * b;
#pragma unroll
    for (int msk = 32; msk; msk >>= 1) { sa += __shfl_xor(sa, msk); sb += __shfl_xor(sb, msk); }
    float ia = 1.f / fmaxf(sqrtf(sa), 1e-12f);
    float ib = 1.f / fmaxf(sqrtf(sb), 1e-12f);
    out[row * 64 + lane] += 0.02f * (a * ia + b * ib);
}

__global__ void loss_write_kernel(const float* __restrict__ acc, float* __restrict__ out) {
    out[0] = acc[0];
}

extern "C" void kernel_launch(void* const* d_in, const int* in_sizes, int n_in,
                              void* d_out, int out_size, void* d_ws, size_t ws_size,
                              hipStream_t stream) {
    const float* user_emb = (const float*)d_in[0];
    const float* item_emb = (const float*)d_in[1];
    const float* user_pre = (const float*)d_in[2];
    const float* item_pre = (const float*)d_in[3];
    const float* img_i = (const float*)d_in[4];
    const float* txt_i = (const float*)d_in[5];
    const float* img_u = (const float*)d_in[6];
    const float* txt_u = (const float*)d_in[7];
    const int* rows = (const int*)d_in[8];
    const int* cols = (const int*)d_in[9];
    const float* vals = (const float*)d_in[10];
    const float* ut = (const float*)d_in[11];
    const float* vt = (const float*)d_in[12];
    const float* u_mul_s = (const float*)d_in[13];
    const float* v_mul_s = (const float*)d_in[14];
    const int* uids = (const int*)d_in[15];
    const int* iids = (const int*)d_in[16];

    float* ws = (float*)d_ws;
    float* zu1 = ws + ZU1;
    float* zi1 = ws + ZI1;
    float2* edge = (float2*)(ws + EDGE);
    float* P = ws + P_OFF;
    float* Q = ws + Q_OFF;
    float* acc = ws + ACC_OFF;
    int* cnt = (int*)(ws + CNT_OFF);
    int* off = (int*)(ws + OFF_OFF);
    int* bcnt = (int*)(ws + BCNT_OFF);
    int* boff = (int*)(ws + BOFF_OFF);
    int* bsum = (int*)(ws + BSUM_OFF);
    float* eu0 = ws + EU0;
    float* ei0 = ws + EI0;
    float* part_u = ws + PART_U;
    float* part_i = ws + PART_I;
    int* bh = (int*)(ws + BH_OFF);
    int* bhp = (int*)(ws + BHP_OFF);
    float2* stage_sv = (float2*)(ws + STAGE_SV);
    short* ebu16 = (short*)(ws + EBU16);
    short* ebi16 = (short*)(ws + EBI16);
    short* gbu16 = (short*)(ws + GBU16);
    short* gbi16 = (short*)(ws + GBI16);

    float* out_u = (float*)d_out;
    float* out_i = out_u + (size_t)N_U * 64;
    float* out_loss = out_u + (size_t)(N_U + N_I) * 64;

    const int NB2 = (NBUCK + 255) / 256;  // 37 bucket-scan blocks

    // zero P,Q,acc only (cnt/off now written directly by place2)
    hipMemsetAsync(ws + P_OFF, 0, 704 * sizeof(float), stream);

    // ---- atomic-free CSR/CSC build (staging overlays ZU1+ZI1; runs before spmm) ----
    bhist_kernel<<<NPB, 256, 0, stream>>>(rows, cols, bh);
    bucket_offsets_kernel<<<(NBUCK * 64 + 255) / 256, 256, 0, stream>>>(bh, bhp, bcnt);
    scan1_kernel<<<NB2, 256, 0, stream>>>(bcnt, bsum, NBUCK);
    scan2_kernel<<<1, 1024, 0, stream>>>(bsum, NB2);
    scan3_kernel<<<NB2, 256, 0, stream>>>(bcnt, bsum, boff, NBUCK);
    bucket_place_kernel<<<NPB, 256, 0, stream>>>(rows, cols, vals, boff, bhp, stage_sv);
    place2_kernel<<<NBUCK, 256, 0, stream>>>(stage_sv, boff, bcnt, off, cnt, edge);

    // E0 = pre + emb
    ew_add_kernel<<<6250, 256, 0, stream>>>((const float4*)user_emb, (const float4*)user_pre,
                                            (float4*)eu0, 1600000);
    ew_add_kernel<<<3125, 256, 0, stream>>>((const float4*)item_emb, (const float4*)item_pre,
                                            (float4*)ei0, 800000);
    // layer-1 rank reductions
    rank_kernel<<<256, 256, 0, stream>>>(ei0, vt, P, N_I);
    rank_kernel<<<256, 256, 0, stream>>>(eu0, ut, Q, N_U);
    // layer-1 SpMM (CSR, no atomics; staging sv now dead -> zu1/zi1 regions free)
    spmm_csr_kernel<<<N_U / 4, 256, 0, stream>>>(edge, off, cnt, 0, ei0, zu1, 1.f, 0, N_U);
    spmm_csr_kernel<<<N_I / 4, 256, 0, stream>>>(edge, off, cnt, N_U, eu0, zi1, 1.f, 0, N_I);
    // layer-2 rank reductions
    rank_kernel<<<256, 256, 0, stream>>>(zi1, vt, P, N_I);
    rank_kernel<<<256, 256, 0, stream>>>(zu1, ut, Q, N_U);
    // out = (E0 + Z1)/3, then layer-2 SpMM accumulates Z2/3 into out
    pre_out_kernel<<<6250, 256, 0, stream>>>((const float4*)eu0, (const float4*)zu1,
                                             (float4*)out_u, 1600000);
    pre_out_kernel<<<3125, 256, 0, stream>>>((const float4*)ei0, (const float4*)zi1,
                                             (float4*)out_i, 800000);
    spmm_csr_kernel<<<N_U / 4, 256, 0, stream>>>(edge, off, cnt, 0, zi1, out_u, 1.f / 3.f, 1,
                                                 N_U);
    spmm_csr_kernel<<<N_I / 4, 256, 0, stream>>>(edge, off, cnt, N_U, zu1, out_i, 1.f / 3.f, 1,
                                                 N_I);
    // bf16 copies of E (overlay in dead zu1 region; zero-padded tail rows)
    conv_bf16_kernel<<<(NPAD_U * 64 + 255) / 256, 256, 0, stream>>>(out_u, ebu16, N_U * 64,
                                                                   NPAD_U * 64);
    conv_bf16_kernel<<<(NPAD_I * 64 + 255) / 256, 256, 0, stream>>>(out_i, ebi16, N_I * 64,
                                                                   NPAD_I * 64);
    // sampled G rows (bf16) + pos term (fp32)
    gather_kernel<<<M_U / 4, 256, 0, stream>>>(uids, M_U, eu0, P, u_mul_s, out_u, gbu16, acc,
                                               -4.f / M_U);
    gather_kernel<<<M_I / 4, 256, 0, stream>>>(iids, M_I, ei0, Q, v_mul_s, out_i, gbi16, acc,
                                               -4.f / M_I);
    // neg term: MFMA exp-sum
    dim3 gu(M_U / 64, NCH_U);
    neg_mfma_kernel<<<gu, 256, 0, stream>>>(gbu16, ebu16, part_u, NCH_U);
    dim3 gi(M_I / 64, NCH_I);
    neg_mfma_kernel<<<gi, 256, 0, stream>>>(gbi16, ebi16, part_i, NCH_I);
    combine_kernel<<<(M_U + 255) / 256, 256, 0, stream>>>(part_u, M_U, NCH_U,
                                                          (float)(NPAD_U - N_U), acc, 4.f / M_U);
    combine_kernel<<<(M_I + 255) / 256, 256, 0, stream>>>(part_i, M_I, NCH_I,
                                                          (float)(NPAD_I - N_I), acc, 4.f / M_I);
    // cat-rate terms (after loss consumed E from d_out)
    cat_kernel<<<(N_U * 64 + 255) / 256, 256, 0, stream>>>(img_u, txt_u, out_u, N_U);
    cat_kernel<<<(N_I * 64 + 255) / 256, 256, 0, stream>>>(img_i, txt_i, out_i, N_I);
    loss_write_kernel<<<1, 1, 0, stream>>>(acc, out_loss);
}